// Round 5
// baseline (968.442 us; speedup 1.0000x reference)
//
#include <hip/hip_runtime.h>

#define NN 50000
#define NE 1600000
#define FIN 128
#define FOUT 64
#define ALPHA 0.2f

#define RANGE 128          // destination nodes per bucket
#define NB 391             // ceil(NN / RANGE)
#define EPB 2048           // edges per block in pass A / bucket-hist (512 thr x 4)

// ---------- int width sniffer: int32 (0) vs int64 (1) ----------
__global__ void k_sniff(const int* __restrict__ edge32, int* __restrict__ iflag) {
    __shared__ int zodd;
    if (threadIdx.x == 0) zodd = 0;
    __syncthreads();
    int z = 0;
    for (int i = threadIdx.x; i < 2048; i += 256)
        if (edge32[2 * i + 1] == 0) z++;        // int64 high words are always 0
    atomicAdd(&zodd, z);
    __syncthreads();
    if (threadIdx.x == 0) *iflag = (zodd > 2000) ? 1 : 0;
}

__device__ inline int ldi(const void* p, size_t i, int isi64) {
    int v = isi64 ? (int)((const long long*)p)[i] : ((const int*)p)[i];
    return v < 0 ? 0 : (v >= NN ? NN - 1 : v);  // clamp: no data-dependent OOB
}

// f32 -> bf16 round-to-nearest-even
__device__ inline unsigned short f2bf(float x) {
    unsigned u = __float_as_uint(x);
    return (unsigned short)((u + 0x7FFFu + ((u >> 16) & 1u)) >> 16);
}

// ---------- K0: u = W @ {a1l,a1r,a2l,a2r} ----------
__global__ void k_u(const float* __restrict__ W, const float* __restrict__ a1,
                    const float* __restrict__ a2, float* __restrict__ u) {
    int k = threadIdx.x;  // 0..127
    float u1 = 0.f, u2 = 0.f, u3 = 0.f, u4 = 0.f;
    for (int j = 0; j < FOUT; j++) {
        float w = W[k * FOUT + j];
        u1 += w * a1[j];
        u2 += w * a1[FOUT + j];
        u3 += w * a2[j];
        u4 += w * a2[FOUT + j];
    }
    u[k] = u1; u[128 + k] = u2; u[256 + k] = u3; u[384 + k] = u4;
}

// ---------- K1: h = input @ W  (N x 64, stored bf16 — consumed only by k_bagg) ----------
__global__ __launch_bounds__(256) void k_gemm(const float* __restrict__ X,
                                              const float* __restrict__ W,
                                              unsigned short* __restrict__ h) {
    __shared__ float wlds[FIN * FOUT];      // 32 KB
    __shared__ float xlds[4][4][FIN];       // 8 KB
    int tid = threadIdx.x;
    for (int i = tid; i < FIN * FOUT; i += 256) wlds[i] = W[i];
    int wave = tid >> 6, lane = tid & 63;
    int base = blockIdx.x * 16 + wave * 4;  // 3125*16 = 50000 exact
    for (int n0 = 0; n0 < 4; n0++) {
        float2 b = ((const float2*)(X + (size_t)(base + n0) * FIN))[lane];
        xlds[wave][n0][2 * lane] = b.x;
        xlds[wave][n0][2 * lane + 1] = b.y;
    }
    __syncthreads();
    float a0 = 0.f, a1v = 0.f, a2v = 0.f, a3 = 0.f;
    for (int k = 0; k < FIN; k++) {
        float w = wlds[k * FOUT + lane];
        a0  += xlds[wave][0][k] * w;
        a1v += xlds[wave][1][k] * w;
        a2v += xlds[wave][2][k] * w;
        a3  += xlds[wave][3][k] * w;
    }
    h[(size_t)(base + 0) * FOUT + lane] = f2bf(a0);
    h[(size_t)(base + 1) * FOUT + lane] = f2bf(a1v);
    h[(size_t)(base + 2) * FOUT + lane] = f2bf(a2v);
    h[(size_t)(base + 3) * FOUT + lane] = f2bf(a3);
}

// ---------- K1b: per-node score scalars (one wave per node) ----------
__global__ __launch_bounds__(256) void k_svec(const float* __restrict__ input,
                                              const float* __restrict__ p_h,
                                              const float* __restrict__ new_h,
                                              const float* __restrict__ u,
                                              float* __restrict__ s1, float* __restrict__ s2,
                                              float* __restrict__ s3, float* __restrict__ s4) {
    int lane = threadIdx.x & 63;
    int v = blockIdx.x * 4 + (threadIdx.x >> 6);
    size_t row = (size_t)v * FIN;
    float2 bi = ((const float2*)(input + row))[lane];
    float2 bp = ((const float2*)(p_h   + row))[lane];
    float2 bn = ((const float2*)(new_h + row))[lane];
    float p1 = bi.x * u[2 * lane]       + bi.y * u[2 * lane + 1];
    float p2 = bp.x * u[128 + 2 * lane] + bp.y * u[128 + 2 * lane + 1];
    float p3 = bn.x * u[256 + 2 * lane] + bn.y * u[256 + 2 * lane + 1];
    float p4 = bi.x * u[384 + 2 * lane] + bi.y * u[384 + 2 * lane + 1];
#pragma unroll
    for (int off = 32; off > 0; off >>= 1) {
        p1 += __shfl_down(p1, off, 64);
        p2 += __shfl_down(p2, off, 64);
        p3 += __shfl_down(p3, off, 64);
        p4 += __shfl_down(p4, off, 64);
    }
    if (lane == 0) { s1[v] = p1; s2[v] = p2; s3[v] = p3; s4[v] = p4; }
}

// ---------- K2: col score + exp + segment max ----------
__global__ void k_colscore(const float* __restrict__ s1, const float* __restrict__ s2,
                           const void* __restrict__ edge_col, const void* __restrict__ row_i,
                           const int* __restrict__ iflag,
                           float* __restrict__ ec, unsigned int* __restrict__ m) {
    int i = blockIdx.x * 256 + threadIdx.x;
    if (i >= NN) return;
    int i64 = *iflag;
    float cs = s1[ldi(edge_col, i, i64)] + s2[i];
    float l = cs > 0.f ? cs : ALPHA * cs;
    float e = expf(-l);                // > 0 always
    ec[i] = e;
    atomicMax(&m[ldi(row_i, i, i64)], __float_as_uint(e));  // init 0, e>0 -> valid
}

// ---------- K3: ex = exp(ec - m) in place; segment sum ----------
__global__ void k_expsum(float* __restrict__ ec, const unsigned int* __restrict__ m,
                         const void* __restrict__ row_i, const int* __restrict__ iflag,
                         float* __restrict__ ssum) {
    int i = blockIdx.x * 256 + threadIdx.x;
    if (i >= NN) return;
    int r = ldi(row_i, i, *iflag);
    float e = expf(ec[i] - __uint_as_float(m[r]));
    ec[i] = e;
    atomicAdd(&ssum[r], e);
}

// ---------- K4: normalize ----------
__global__ void k_norm(const float* __restrict__ ex, const float* __restrict__ ssum,
                       const void* __restrict__ row_i, const int* __restrict__ iflag,
                       float* __restrict__ ecs) {
    int i = blockIdx.x * 256 + threadIdx.x;
    if (i >= NN) return;
    ecs[i] = ex[i] / (ssum[ldi(row_i, i, *iflag)] + 1e-16f);
}

// ---------- K5a: bucket histogram (391 bins, LDS-privatized, 512 thr) ----------
__global__ __launch_bounds__(512) void k_bhist(const void* __restrict__ edge,
                                               const int* __restrict__ iflag,
                                               int* __restrict__ bcnt) {
    __shared__ int hist[NB];
    int tid = threadIdx.x;
    for (int t = tid; t < NB; t += 512) hist[t] = 0;
    __syncthreads();
    int i64 = *iflag;
    int base = blockIdx.x * EPB;
#pragma unroll
    for (int k = 0; k < 4; k++) {
        int e = base + k * 512 + tid;
        if (e < NE) atomicAdd(&hist[ldi(edge, e, i64) >> 7], 1);
    }
    __syncthreads();
    for (int t = tid; t < NB; t += 512)
        if (hist[t]) atomicAdd(&bcnt[t], hist[t]);
}

// ---------- K5b: scan 391 bucket counts -> bstart, bcur ----------
__global__ __launch_bounds__(512) void k_bscan(const int* __restrict__ bcnt,
                                               int* __restrict__ bstart, int* __restrict__ bcur) {
    __shared__ int s[512];
    int tid = threadIdx.x;
    int x = (tid < NB) ? bcnt[tid] : 0;
    s[tid] = x;
    __syncthreads();
    for (int off = 1; off < 512; off <<= 1) {
        int t = (tid >= off) ? s[tid - off] : 0;
        __syncthreads();
        s[tid] += t;
        __syncthreads();
    }
    if (tid < NB) { int e = s[tid] - x; bstart[tid] = e; bcur[tid] = e; }
    if (tid == 0) bstart[NB] = NE;
}

// ---------- K5c pass A: per-edge score + LDS-binned coarse scatter (512 thr) ----------
// Records {e0|e1<<16, ee} land as contiguous per-(block,bucket) runs in tmp
// (~5 records/run at RANGE=128 -> ~2.5x write amp on tmp, still dense enough).
__global__ __launch_bounds__(512) void k_edgeA(const float* __restrict__ s3, const float* __restrict__ s4,
                                               const float* __restrict__ ecs,
                                               const void* __restrict__ edge, const void* __restrict__ row_resort,
                                               const int* __restrict__ iflag,
                                               int* __restrict__ bcur, uint2* __restrict__ tmp,
                                               float* __restrict__ edge_e /* = out2 */) {
    __shared__ int hist[NB];
    __shared__ int bbase[NB];
    int tid = threadIdx.x;
    for (int t = tid; t < NB; t += 512) hist[t] = 0;
    __syncthreads();
    int i64 = *iflag;
    int base = blockIdx.x * EPB;
    unsigned int key[4]; float val[4]; int rk[4], bk[4];
#pragma unroll
    for (int k = 0; k < 4; k++) {
        int e = base + k * 512 + tid;
        bk[k] = -1;
        if (e < NE) {
            int e0 = ldi(edge, e, i64);
            int e1 = ldi(edge, (size_t)NE + e, i64);
            int rr = ldi(row_resort, e, i64);
            float rs = s3[rr] + s4[e1];
            float l = rs > 0.f ? rs : ALPHA * rs;
            float ee = expf(-l) * ecs[rr];
            edge_e[e] = ee;                           // numerator for out2 (sequential)
            key[k] = (unsigned int)e0 | ((unsigned int)e1 << 16);  // both < 65536
            val[k] = ee;
            bk[k] = e0 >> 7;                          // bucket = e0 / RANGE
            rk[k] = atomicAdd(&hist[bk[k]], 1);       // rank within (block, bucket)
        }
    }
    __syncthreads();
    for (int t = tid; t < NB; t += 512)
        bbase[t] = atomicAdd(&bcur[t], hist[t]);      // reserve contiguous run
    __syncthreads();
#pragma unroll
    for (int k = 0; k < 4; k++)
        if (bk[k] >= 0)
            tmp[bbase[bk[k]] + rk[k]] = make_uint2(key[k], __float_as_uint(val[k]));
}

// ---------- K6: bucket-parallel aggregate (replaces k_edgeB + k_agg) ----------
// One block per bucket; LDS f32 accumulator tile [128 nodes][65 (pad)] + rowsum.
// Waves stream the bucket's records (sequential, L2-hot), gather bf16 h rows
// (2 records per instruction, uint per lane), and ds_add_f32 into the tile
// (fire-and-forget; worst-case 4-way bank conflict when both halves hit the
// same node row). Epilogue: rowsum fixup + divide + elu + coalesced writes.
__global__ __launch_bounds__(512) void k_bagg(const unsigned short* __restrict__ h,
                                              const uint2* __restrict__ tmp,
                                              const int* __restrict__ bstart,
                                              float* __restrict__ ersum,
                                              float* __restrict__ out0) {
    __shared__ float lacc[RANGE * 65];
    __shared__ float lrs[RANGE];
    int tid = threadIdx.x;
    int b = blockIdx.x;
    int v0 = b * RANGE;
    for (int i = tid; i < RANGE * 65; i += 512) lacc[i] = 0.f;
    if (tid < RANGE) lrs[tid] = 0.f;
    __syncthreads();
    int lo = bstart[b], hi = bstart[b + 1];
    int lane = tid & 63, wid = tid >> 6;
    int half = lane >> 5, fl = lane & 31;             // feats 2fl, 2fl+1
    for (int j = lo + wid * 2; j < hi; j += 16) {     // 8 waves x 2 records/iter
        int e = j + half;
        uint2 r = (e < hi) ? tmp[e] : make_uint2(0u, 0u);   // inactive: ee=0, harmless
        float ee = __uint_as_float(r.y);
        int row = (int)(r.x & (RANGE - 1));
        unsigned hh = *(const unsigned*)(h + (((size_t)(r.x >> 16)) << 6) + 2 * fl);
        atomicAdd(&lacc[row * 65 + 2 * fl],     ee * __uint_as_float(hh << 16));
        atomicAdd(&lacc[row * 65 + 2 * fl + 1], ee * __uint_as_float(hh & 0xFFFF0000u));
        if (fl == 0) atomicAdd(&lrs[row], ee);
    }
    __syncthreads();
    for (int i = tid; i < RANGE * FOUT; i += 512) {
        int r = i >> 6, f = i & 63;
        int v = v0 + r;
        if (v < NN) {
            float rs = lrs[r];
            rs += (rs == 0.f) ? 1.f : 0.f;            // empty-segment fixup
            float hp = lacc[r * 65 + f] / rs;
            out0[(size_t)v * FOUT + f] = hp > 0.f ? hp : expm1f(hp);
            if (f == 0) ersum[v] = rs;
        }
    }
}

// ---------- K7: out2 = numerator / rowsum, in place ----------
__global__ void k_att(const void* __restrict__ edge, const int* __restrict__ iflag,
                      const float* __restrict__ ersum, float* __restrict__ out2) {
    int e = blockIdx.x * 256 + threadIdx.x;           // 6250*256 = NE exact
    out2[e] = out2[e] / ersum[ldi(edge, e, *iflag)];
}

// ---------- K8: out1 = float(edge), runs LAST (overwrites tmp scratch) ----------
__global__ void k_edgecopy(const void* __restrict__ edge, const int* __restrict__ iflag,
                           float* __restrict__ out1) {
    int i = blockIdx.x * 256 + threadIdx.x;           // 12500*256 = 2*NE exact
    int i64 = *iflag;
    int v = i64 ? (int)((const long long*)edge)[i] : ((const int*)edge)[i];
    out1[i] = (float)v;
}

extern "C" void kernel_launch(void* const* d_in, const int* in_sizes, int n_in,
                              void* d_out, int out_size, void* d_ws, size_t ws_size,
                              hipStream_t stream) {
    // Resolve inputs by element count (all distinct).
    int ix[3] = {0, 1, 2}; int nx = 0;
    int iE = 3, iCol = 4, iRowI = 5, iRes = 6, iW = 8, iA1 = 9, iA2 = 10;
    bool a1seen = false;
    for (int i = 0; i < n_in; i++) {
        int s = in_sizes[i];
        if (s == NN * FIN) { if (nx < 3) ix[nx++] = i; }
        else if (s == 2 * NE) iE = i;
        else if (s == 2 * NN) iCol = i;
        else if (s == NN) iRowI = i;
        else if (s == NE) iRes = i;
        else if (s == FIN * FOUT) iW = i;
        else if (s == 2 * FOUT) { if (!a1seen) { iA1 = i; a1seen = true; } else iA2 = i; }
    }
    const float* input = (const float*)d_in[ix[0]];
    const float* p_h   = (const float*)d_in[ix[1]];
    const float* new_h = (const float*)d_in[ix[2]];
    const void* edge       = d_in[iE];
    const void* edge_col   = d_in[iCol];
    const void* row_i      = d_in[iRowI];
    const void* row_resort = d_in[iRes];
    const float* W  = (const float*)d_in[iW];
    const float* a1 = (const float*)d_in[iA1];
    const float* a2 = (const float*)d_in[iA2];

    // Outputs are FLOAT32, concatenated.
    float* out0 = (float*)d_out;                      // N*FOUT
    float* out1 = out0 + (size_t)NN * FOUT;           // 2*NE
    float* out2 = out1 + (size_t)2 * NE;              // NE (edge_e numerator, then in-place divide)

    // Coarse-scatter scratch: out1 region is free until k_edgecopy (last kernel).
    // 2*NE floats = NE * 8 bytes = exactly NE uint2 records. 8B-aligned.
    uint2* tmp = (uint2*)out1;

    // ws layout (~14 MB)
    unsigned short* h = (unsigned short*)d_ws;        // NN*FOUT bf16 (6.4 MB)
    float*  s1     = (float*)d_ws + (size_t)NN * FOUT / 2;
    float*  s2     = s1 + NN;
    float*  s3     = s2 + NN;
    float*  s4     = s3 + NN;
    float*  ec     = s4 + NN;                         // reused in place as ex
    float*  ecs    = ec + NN;
    float*  mseg   = ecs + NN;                        // zeroed (atomicMax uint bits)
    float*  ssum   = mseg + NN;                       // zeroed
    int*    bcnt   = (int*)(ssum + NN);               // NB, zeroed (contiguous with above)
    int*    bstart = bcnt + NB;                       // NB+1
    int*    bcur   = bstart + NB + 1;                 // NB
    float*  ersum  = (float*)(bcur + NB);             // NN (plain stores, no zero needed)
    float*  u      = ersum + NN;                      // 512
    int*    iflag  = (int*)(u + 512);

    hipMemsetAsync(mseg, 0, ((size_t)2 * NN + NB) * sizeof(float), stream);  // mseg, ssum, bcnt

    k_sniff<<<1, 256, 0, stream>>>((const int*)edge, iflag);
    k_u<<<1, 128, 0, stream>>>(W, a1, a2, u);
    k_gemm<<<NN / 16, 256, 0, stream>>>(input, W, h);
    k_svec<<<NN / 4, 256, 0, stream>>>(input, p_h, new_h, u, s1, s2, s3, s4);
    k_colscore<<<(NN + 255) / 256, 256, 0, stream>>>(s1, s2, edge_col, row_i, iflag, ec, (unsigned int*)mseg);
    k_expsum<<<(NN + 255) / 256, 256, 0, stream>>>(ec, (const unsigned int*)mseg, row_i, iflag, ssum);
    k_norm<<<(NN + 255) / 256, 256, 0, stream>>>(ec, ssum, row_i, iflag, ecs);
    k_bhist<<<(NE + EPB - 1) / EPB, 512, 0, stream>>>(edge, iflag, bcnt);
    k_bscan<<<1, 512, 0, stream>>>(bcnt, bstart, bcur);
    k_edgeA<<<(NE + EPB - 1) / EPB, 512, 0, stream>>>(s3, s4, ecs, edge, row_resort, iflag, bcur, tmp, out2);
    k_bagg<<<NB, 512, 0, stream>>>(h, tmp, bstart, ersum, out0);
    k_att<<<NE / 256, 256, 0, stream>>>(edge, iflag, ersum, out2);
    k_edgecopy<<<2 * NE / 256, 256, 0, stream>>>(edge, iflag, out1);
}

// Round 6
// 330.464 us; speedup vs baseline: 2.9306x; 2.9306x over previous
//
#include <hip/hip_runtime.h>

#define NN 50000
#define NE 1600000
#define FIN 128
#define FOUT 64
#define ALPHA 0.2f

#define RANGE 256          // destination nodes per bucket
#define NB 196             // ceil(NN / RANGE)
#define EPB 2048           // edges per block in pass A / bucket-hist (512 thr x 4)

// ---------- int width sniffer: int32 (0) vs int64 (1) ----------
__global__ void k_sniff(const int* __restrict__ edge32, int* __restrict__ iflag) {
    __shared__ int zodd;
    if (threadIdx.x == 0) zodd = 0;
    __syncthreads();
    int z = 0;
    for (int i = threadIdx.x; i < 2048; i += 256)
        if (edge32[2 * i + 1] == 0) z++;        // int64 high words are always 0
    atomicAdd(&zodd, z);
    __syncthreads();
    if (threadIdx.x == 0) *iflag = (zodd > 2000) ? 1 : 0;
}

__device__ inline int ldi(const void* p, size_t i, int isi64) {
    int v = isi64 ? (int)((const long long*)p)[i] : ((const int*)p)[i];
    return v < 0 ? 0 : (v >= NN ? NN - 1 : v);  // clamp: no data-dependent OOB
}

// f32 -> bf16 round-to-nearest-even
__device__ inline unsigned short f2bf(float x) {
    unsigned u = __float_as_uint(x);
    return (unsigned short)((u + 0x7FFFu + ((u >> 16) & 1u)) >> 16);
}

// ---------- K0: u = W @ {a1l,a1r,a2l,a2r} ----------
__global__ void k_u(const float* __restrict__ W, const float* __restrict__ a1,
                    const float* __restrict__ a2, float* __restrict__ u) {
    int k = threadIdx.x;  // 0..127
    float u1 = 0.f, u2 = 0.f, u3 = 0.f, u4 = 0.f;
    for (int j = 0; j < FOUT; j++) {
        float w = W[k * FOUT + j];
        u1 += w * a1[j];
        u2 += w * a1[FOUT + j];
        u3 += w * a2[j];
        u4 += w * a2[FOUT + j];
    }
    u[k] = u1; u[128 + k] = u2; u[256 + k] = u3; u[384 + k] = u4;
}

// ---------- K1: h = input @ W  (N x 64, stored bf16 — consumed only by k_agg) ----------
__global__ __launch_bounds__(256) void k_gemm(const float* __restrict__ X,
                                              const float* __restrict__ W,
                                              unsigned short* __restrict__ h) {
    __shared__ float wlds[FIN * FOUT];      // 32 KB
    __shared__ float xlds[4][4][FIN];       // 8 KB
    int tid = threadIdx.x;
    for (int i = tid; i < FIN * FOUT; i += 256) wlds[i] = W[i];
    int wave = tid >> 6, lane = tid & 63;
    int base = blockIdx.x * 16 + wave * 4;  // 3125*16 = 50000 exact
    for (int n0 = 0; n0 < 4; n0++) {
        float2 b = ((const float2*)(X + (size_t)(base + n0) * FIN))[lane];
        xlds[wave][n0][2 * lane] = b.x;
        xlds[wave][n0][2 * lane + 1] = b.y;
    }
    __syncthreads();
    float a0 = 0.f, a1v = 0.f, a2v = 0.f, a3 = 0.f;
    for (int k = 0; k < FIN; k++) {
        float w = wlds[k * FOUT + lane];
        a0  += xlds[wave][0][k] * w;
        a1v += xlds[wave][1][k] * w;
        a2v += xlds[wave][2][k] * w;
        a3  += xlds[wave][3][k] * w;
    }
    h[(size_t)(base + 0) * FOUT + lane] = f2bf(a0);
    h[(size_t)(base + 1) * FOUT + lane] = f2bf(a1v);
    h[(size_t)(base + 2) * FOUT + lane] = f2bf(a2v);
    h[(size_t)(base + 3) * FOUT + lane] = f2bf(a3);
}

// ---------- K1b: per-node score scalars (one wave per node) ----------
__global__ __launch_bounds__(256) void k_svec(const float* __restrict__ input,
                                              const float* __restrict__ p_h,
                                              const float* __restrict__ new_h,
                                              const float* __restrict__ u,
                                              float* __restrict__ s1, float* __restrict__ s2,
                                              float* __restrict__ s3, float* __restrict__ s4) {
    int lane = threadIdx.x & 63;
    int v = blockIdx.x * 4 + (threadIdx.x >> 6);
    size_t row = (size_t)v * FIN;
    float2 bi = ((const float2*)(input + row))[lane];
    float2 bp = ((const float2*)(p_h   + row))[lane];
    float2 bn = ((const float2*)(new_h + row))[lane];
    float p1 = bi.x * u[2 * lane]       + bi.y * u[2 * lane + 1];
    float p2 = bp.x * u[128 + 2 * lane] + bp.y * u[128 + 2 * lane + 1];
    float p3 = bn.x * u[256 + 2 * lane] + bn.y * u[256 + 2 * lane + 1];
    float p4 = bi.x * u[384 + 2 * lane] + bi.y * u[384 + 2 * lane + 1];
#pragma unroll
    for (int off = 32; off > 0; off >>= 1) {
        p1 += __shfl_down(p1, off, 64);
        p2 += __shfl_down(p2, off, 64);
        p3 += __shfl_down(p3, off, 64);
        p4 += __shfl_down(p4, off, 64);
    }
    if (lane == 0) { s1[v] = p1; s2[v] = p2; s3[v] = p3; s4[v] = p4; }
}

// ---------- K2: col score + exp + segment max ----------
__global__ void k_colscore(const float* __restrict__ s1, const float* __restrict__ s2,
                           const void* __restrict__ edge_col, const void* __restrict__ row_i,
                           const int* __restrict__ iflag,
                           float* __restrict__ ec, unsigned int* __restrict__ m) {
    int i = blockIdx.x * 256 + threadIdx.x;
    if (i >= NN) return;
    int i64 = *iflag;
    float cs = s1[ldi(edge_col, i, i64)] + s2[i];
    float l = cs > 0.f ? cs : ALPHA * cs;
    float e = expf(-l);                // > 0 always
    ec[i] = e;
    atomicMax(&m[ldi(row_i, i, i64)], __float_as_uint(e));  // init 0, e>0 -> valid
}

// ---------- K3: ex = exp(ec - m) in place; segment sum ----------
__global__ void k_expsum(float* __restrict__ ec, const unsigned int* __restrict__ m,
                         const void* __restrict__ row_i, const int* __restrict__ iflag,
                         float* __restrict__ ssum) {
    int i = blockIdx.x * 256 + threadIdx.x;
    if (i >= NN) return;
    int r = ldi(row_i, i, *iflag);
    float e = expf(ec[i] - __uint_as_float(m[r]));
    ec[i] = e;
    atomicAdd(&ssum[r], e);
}

// ---------- K4: normalize ----------
__global__ void k_norm(const float* __restrict__ ex, const float* __restrict__ ssum,
                       const void* __restrict__ row_i, const int* __restrict__ iflag,
                       float* __restrict__ ecs) {
    int i = blockIdx.x * 256 + threadIdx.x;
    if (i >= NN) return;
    ecs[i] = ex[i] / (ssum[ldi(row_i, i, *iflag)] + 1e-16f);
}

// ---------- K5a: bucket histogram (196 bins, LDS-privatized, 512 thr) ----------
__global__ __launch_bounds__(512) void k_bhist(const void* __restrict__ edge,
                                               const int* __restrict__ iflag,
                                               int* __restrict__ bcnt) {
    __shared__ int hist[NB];
    int tid = threadIdx.x;
    for (int t = tid; t < NB; t += 512) hist[t] = 0;
    __syncthreads();
    int i64 = *iflag;
    int base = blockIdx.x * EPB;
#pragma unroll
    for (int k = 0; k < 4; k++) {
        int e = base + k * 512 + tid;
        if (e < NE) atomicAdd(&hist[ldi(edge, e, i64) >> 8], 1);
    }
    __syncthreads();
    for (int t = tid; t < NB; t += 512)
        if (hist[t]) atomicAdd(&bcnt[t], hist[t]);
}

// ---------- K5b: scan 196 bucket counts -> bstart, bcur; sentinels ----------
__global__ __launch_bounds__(256) void k_bscan(const int* __restrict__ bcnt,
                                               int* __restrict__ bstart, int* __restrict__ bcur,
                                               int* __restrict__ start) {
    __shared__ int s[256];
    int tid = threadIdx.x;
    int x = (tid < NB) ? bcnt[tid] : 0;
    s[tid] = x;
    __syncthreads();
    for (int off = 1; off < 256; off <<= 1) {
        int t = (tid >= off) ? s[tid - off] : 0;
        __syncthreads();
        s[tid] += t;
        __syncthreads();
    }
    if (tid < NB) { int e = s[tid] - x; bstart[tid] = e; bcur[tid] = e; }
    if (tid == 0) { bstart[NB] = NE; start[NN] = NE; }
}

// ---------- K5c pass A: per-edge score + LDS-binned coarse scatter (512 thr) ----------
__global__ __launch_bounds__(512) void k_edgeA(const float* __restrict__ s3, const float* __restrict__ s4,
                                               const float* __restrict__ ecs,
                                               const void* __restrict__ edge, const void* __restrict__ row_resort,
                                               const int* __restrict__ iflag,
                                               int* __restrict__ bcur, uint2* __restrict__ tmp,
                                               float* __restrict__ edge_e /* = out2 */) {
    __shared__ int hist[NB];
    __shared__ int bbase[NB];
    int tid = threadIdx.x;
    for (int t = tid; t < NB; t += 512) hist[t] = 0;
    __syncthreads();
    int i64 = *iflag;
    int base = blockIdx.x * EPB;
    unsigned int key[4]; float val[4]; int rk[4], bk[4];
#pragma unroll
    for (int k = 0; k < 4; k++) {
        int e = base + k * 512 + tid;
        bk[k] = -1;
        if (e < NE) {
            int e0 = ldi(edge, e, i64);
            int e1 = ldi(edge, (size_t)NE + e, i64);
            int rr = ldi(row_resort, e, i64);
            float rs = s3[rr] + s4[e1];
            float l = rs > 0.f ? rs : ALPHA * rs;
            float ee = expf(-l) * ecs[rr];
            edge_e[e] = ee;                           // numerator for out2 (sequential)
            key[k] = (unsigned int)e0 | ((unsigned int)e1 << 16);  // both < 65536
            val[k] = ee;
            bk[k] = e0 >> 8;                          // bucket = e0 / RANGE
            rk[k] = atomicAdd(&hist[bk[k]], 1);       // rank within (block, bucket)
        }
    }
    __syncthreads();
    for (int t = tid; t < NB; t += 512)
        bbase[t] = atomicAdd(&bcur[t], hist[t]);      // reserve contiguous run
    __syncthreads();
#pragma unroll
    for (int k = 0; k < 4; k++)
        if (bk[k] >= 0)
            tmp[bbase[bk[k]] + rk[k]] = make_uint2(key[k], __float_as_uint(val[k]));
}

// ---------- K5c pass B: per-node offsets + fine scatter, L2-resident ----------
__global__ __launch_bounds__(512) void k_edgeB(const uint2* __restrict__ tmp,
                                               const int* __restrict__ bstart,
                                               int* __restrict__ start,
                                               float2* __restrict__ pairs) {
    __shared__ int cnt[RANGE];
    __shared__ int s[RANGE];
    __shared__ int cur[RANGE];
    int b = blockIdx.x;
    int tid = threadIdx.x;
    int v0 = b * RANGE;
    if (tid < RANGE) cnt[tid] = 0;
    __syncthreads();
    int lo = bstart[b], hi = bstart[b + 1];
    for (int i = lo + tid; i < hi; i += 512)
        atomicAdd(&cnt[tmp[i].x & 0xFFu], 1);         // e0 & 255 == e0 - v0
    __syncthreads();
    if (tid < RANGE) s[tid] = cnt[tid];
    __syncthreads();
    for (int off = 1; off < RANGE; off <<= 1) {
        int t = 0;
        if (tid < RANGE && tid >= off) t = s[tid - off];
        __syncthreads();
        if (tid < RANGE) s[tid] += t;
        __syncthreads();
    }
    if (tid < RANGE) {
        int g = lo + s[tid] - cnt[tid];               // exclusive prefix + bucket base
        cur[tid] = g;
        int v = v0 + tid;
        if (v < NN) start[v] = g;
    }
    __syncthreads();
    for (int i = lo + tid; i < hi; i += 512) {
        uint2 r = tmp[i];
        int pos = atomicAdd(&cur[r.x & 0xFFu], 1);    // LDS atomic
        pairs[pos] = make_float2(__int_as_float((int)(r.x >> 16)), __uint_as_float(r.y));
    }
}

// ---------- K6: gather-aggregate per node; 4 edges per wave-instruction ----------
// One wave per node (8 waves/block). Lane layout: q=lane>>4 edge slot, fq=lane&15
// feature quad. Each lane loads uint2 (4 bf16 feats) -> per 8 edges only
// 2 gathers + 2 pairs loads, 8 edges in flight. Cross-quarter combine via
// shfl_xor(16|32); q==0 lanes write float4.
__global__ __launch_bounds__(512) void k_agg(const unsigned short* __restrict__ h,
                                             const float2* __restrict__ pairs,
                                             const int* __restrict__ start,
                                             float* __restrict__ ersum,
                                             float* __restrict__ out0) {
    int lane = threadIdx.x & 63;
    int q  = lane >> 4;                // edge slot within group of 4
    int fq = lane & 15;                // feature quad: feats 4fq..4fq+3
    int v = blockIdx.x * 8 + (threadIdx.x >> 6);      // 6250*8 = NN exact
    int a = start[v], b = start[v + 1];
    float acc0 = 0.f, acc1 = 0.f, acc2 = 0.f, acc3 = 0.f, rs = 0.f;
    for (int j = a; j < b; j += 8) {
        int eA = j + q, eB = j + 4 + q;
        float2 pA = (eA < b) ? pairs[eA] : make_float2(__int_as_float(0), 0.f);
        float2 pB = (eB < b) ? pairs[eB] : make_float2(__int_as_float(0), 0.f);
        uint2 hA = *(const uint2*)(h + (((size_t)__float_as_int(pA.x)) << 6) + 4 * fq);
        uint2 hB = *(const uint2*)(h + (((size_t)__float_as_int(pB.x)) << 6) + 4 * fq);
        acc0 += pA.y * __uint_as_float(hA.x << 16);
        acc1 += pA.y * __uint_as_float(hA.x & 0xFFFF0000u);
        acc2 += pA.y * __uint_as_float(hA.y << 16);
        acc3 += pA.y * __uint_as_float(hA.y & 0xFFFF0000u);
        acc0 += pB.y * __uint_as_float(hB.x << 16);
        acc1 += pB.y * __uint_as_float(hB.x & 0xFFFF0000u);
        acc2 += pB.y * __uint_as_float(hB.y << 16);
        acc3 += pB.y * __uint_as_float(hB.y & 0xFFFF0000u);
        rs += pA.y + pB.y;
    }
#pragma unroll
    for (int off = 16; off <= 32; off <<= 1) {
        acc0 += __shfl_xor(acc0, off, 64);
        acc1 += __shfl_xor(acc1, off, 64);
        acc2 += __shfl_xor(acc2, off, 64);
        acc3 += __shfl_xor(acc3, off, 64);
        rs   += __shfl_xor(rs, off, 64);
    }
    if (q == 0) {
        rs += (rs == 0.f) ? 1.f : 0.f;                // empty-segment fixup (ee>0 otherwise)
        float4 o;
        o.x = acc0 / rs; o.y = acc1 / rs; o.z = acc2 / rs; o.w = acc3 / rs;
        o.x = o.x > 0.f ? o.x : expm1f(o.x);
        o.y = o.y > 0.f ? o.y : expm1f(o.y);
        o.z = o.z > 0.f ? o.z : expm1f(o.z);
        o.w = o.w > 0.f ? o.w : expm1f(o.w);
        ((float4*)(out0 + (size_t)v * FOUT))[fq] = o;
        if (fq == 0) ersum[v] = rs;                   // fixed rowsum, plain store
    }
}

// ---------- K7: out1 = float(edge) AND out2 /= ersum[e0] (fused, runs LAST) ----------
__global__ __launch_bounds__(256) void k_final(const void* __restrict__ edge, const int* __restrict__ iflag,
                                               const float* __restrict__ ersum,
                                               float* __restrict__ out2, float* __restrict__ out1) {
    int i = blockIdx.x * 256 + threadIdx.x;           // 12500*256 = 2*NE exact
    int i64 = *iflag;
    int v = i64 ? (int)((const long long*)edge)[i] : ((const int*)edge)[i];
    out1[i] = (float)v;
    if (i < NE) {                                     // edge[0..NE) is row 0 = e0
        int e0 = v < 0 ? 0 : (v >= NN ? NN - 1 : v);
        out2[i] = out2[i] / ersum[e0];
    }
}

extern "C" void kernel_launch(void* const* d_in, const int* in_sizes, int n_in,
                              void* d_out, int out_size, void* d_ws, size_t ws_size,
                              hipStream_t stream) {
    // Resolve inputs by element count (all distinct).
    int ix[3] = {0, 1, 2}; int nx = 0;
    int iE = 3, iCol = 4, iRowI = 5, iRes = 6, iW = 8, iA1 = 9, iA2 = 10;
    bool a1seen = false;
    for (int i = 0; i < n_in; i++) {
        int s = in_sizes[i];
        if (s == NN * FIN) { if (nx < 3) ix[nx++] = i; }
        else if (s == 2 * NE) iE = i;
        else if (s == 2 * NN) iCol = i;
        else if (s == NN) iRowI = i;
        else if (s == NE) iRes = i;
        else if (s == FIN * FOUT) iW = i;
        else if (s == 2 * FOUT) { if (!a1seen) { iA1 = i; a1seen = true; } else iA2 = i; }
    }
    const float* input = (const float*)d_in[ix[0]];
    const float* p_h   = (const float*)d_in[ix[1]];
    const float* new_h = (const float*)d_in[ix[2]];
    const void* edge       = d_in[iE];
    const void* edge_col   = d_in[iCol];
    const void* row_i      = d_in[iRowI];
    const void* row_resort = d_in[iRes];
    const float* W  = (const float*)d_in[iW];
    const float* a1 = (const float*)d_in[iA1];
    const float* a2 = (const float*)d_in[iA2];

    // Outputs are FLOAT32, concatenated.
    float* out0 = (float*)d_out;                      // N*FOUT
    float* out1 = out0 + (size_t)NN * FOUT;           // 2*NE
    float* out2 = out1 + (size_t)2 * NE;              // NE (edge_e numerator, then in-place divide)

    // Coarse-scatter scratch: out1 region is free until k_final (last kernel).
    uint2* tmp = (uint2*)out1;

    // ws layout (~27.6 MB; h region reserved as NN*FOUT floats, used as bf16)
    unsigned short* h = (unsigned short*)d_ws;        // NN*FOUT bf16 (6.4 MB used)
    float2* pairs  = (float2*)((float*)d_ws + (size_t)NN * FOUT); // NE float2 (12.8 MB)
    float*  s1     = (float*)(pairs + NE);
    float*  s2     = s1 + NN;
    float*  s3     = s2 + NN;
    float*  s4     = s3 + NN;
    float*  ec     = s4 + NN;                         // reused in place as ex
    float*  ecs    = ec + NN;
    float*  mseg   = ecs + NN;                        // zeroed (atomicMax uint bits)
    float*  ssum   = mseg + NN;                       // zeroed
    int*    bcnt   = (int*)(ssum + NN);               // NB, zeroed (contiguous with above)
    int*    start  = bcnt + NB;                       // NN+1 (sentinel)
    int*    bstart = start + NN + 1;                  // NB+1
    int*    bcur   = bstart + NB + 1;                 // NB
    float*  ersum  = (float*)(bcur + NB);             // NN (plain stores, no zero needed)
    float*  u      = ersum + NN;                      // 512
    int*    iflag  = (int*)(u + 512);

    hipMemsetAsync(mseg, 0, ((size_t)2 * NN + NB) * sizeof(float), stream);  // mseg, ssum, bcnt

    k_sniff<<<1, 256, 0, stream>>>((const int*)edge, iflag);
    k_u<<<1, 128, 0, stream>>>(W, a1, a2, u);
    k_gemm<<<NN / 16, 256, 0, stream>>>(input, W, h);
    k_svec<<<NN / 4, 256, 0, stream>>>(input, p_h, new_h, u, s1, s2, s3, s4);
    k_colscore<<<(NN + 255) / 256, 256, 0, stream>>>(s1, s2, edge_col, row_i, iflag, ec, (unsigned int*)mseg);
    k_expsum<<<(NN + 255) / 256, 256, 0, stream>>>(ec, (const unsigned int*)mseg, row_i, iflag, ssum);
    k_norm<<<(NN + 255) / 256, 256, 0, stream>>>(ec, ssum, row_i, iflag, ecs);
    k_bhist<<<(NE + EPB - 1) / EPB, 512, 0, stream>>>(edge, iflag, bcnt);
    k_bscan<<<1, 256, 0, stream>>>(bcnt, bstart, bcur, start);
    k_edgeA<<<(NE + EPB - 1) / EPB, 512, 0, stream>>>(s3, s4, ecs, edge, row_resort, iflag, bcur, tmp, out2);
    k_edgeB<<<NB, 512, 0, stream>>>(tmp, bstart, start, pairs);
    k_agg<<<NN / 8, 512, 0, stream>>>(h, pairs, start, ersum, out0);
    k_final<<<2 * NE / 256, 256, 0, stream>>>(edge, iflag, ersum, out2, out1);
}